// Round 7
// baseline (755.010 us; speedup 1.0000x reference)
//
#include <hip/hip_runtime.h>

typedef __bf16 bf16x8 __attribute__((ext_vector_type(8)));
typedef __bf16 bf16x4 __attribute__((ext_vector_type(4)));
typedef float f32x4 __attribute__((ext_vector_type(4)));

#define EMBED 584
#define KP 608      // K padded to 19*32 (zero-filled cols 584..607)
#define HEADS 8
#define HS 73
#define HSQ 80      // padded head size in q/k storage (16B-aligned rows)
#define CTX 200
#define NBATCH 256
#define MROWS 51200 // NBATCH*CTX
#define NQKV 1752   // 3*EMBED

// attention P-scratch stride (halfwords): 14 tiles*16 = 224 used + 8 pad.
#define PSS 232

// async global->LDS 16B copy: LDS dest is wave-uniform base + lane*16
__device__ __forceinline__ void gld_lds16(__bf16* lds, const __bf16* g) {
  __builtin_amdgcn_global_load_lds(
      (const __attribute__((address_space(1))) void*)g,
      (__attribute__((address_space(3))) void*)lds, 16, 0, 0);
}

// ---- pack Wq|Wk|Wv|Wo -> bf16 [2336][608] (zero pad cols), fused with
// ---- zeroing of attention pad lanes (grid 2048 = one block per bh) ----
__global__ __launch_bounds__(256) void pack_w_zero(const float* __restrict__ Wq,
                                                   const float* __restrict__ Wk,
                                                   const float* __restrict__ Wv,
                                                   const float* __restrict__ Wo,
                                                   __bf16* __restrict__ out,
                                                   __bf16* __restrict__ qb,
                                                   __bf16* __restrict__ kb,
                                                   __bf16* __restrict__ vb) {
  int bid = blockIdx.x, tid = threadIdx.x;
  if (bid < 694) {
    int i = bid * 256 + tid;
    if (i < 2336 * 76) {
      int r = i / 76, slot = i - r * 76;
      int col = slot * 8;
      bf16x8 o8 = {};
      if (col < EMBED) {
        const float* src = r < 584  ? Wq + (size_t)r * EMBED
                         : r < 1168 ? Wk + (size_t)(r - 584) * EMBED
                         : r < 1752 ? Wv + (size_t)(r - 1168) * EMBED
                                    : Wo + (size_t)(r - 1752) * EMBED;
        const float4* s4 = (const float4*)(src + col);
        float4 f0 = s4[0], f1 = s4[1];
        o8[0] = (__bf16)f0.x; o8[1] = (__bf16)f0.y; o8[2] = (__bf16)f0.z; o8[3] = (__bf16)f0.w;
        o8[4] = (__bf16)f1.x; o8[5] = (__bf16)f1.y; o8[6] = (__bf16)f1.z; o8[7] = (__bf16)f1.w;
      }
      *(bf16x8*)(out + (size_t)r * KP + col) = o8;
    }
  }
  // zero pad lanes for bh = bid: q/k cols 72..79, v pad rows 73..79
  int bh = bid;
  bf16x8 z = {};
  __bf16* qp = qb + (size_t)bh * 16000;
  __bf16* kp = kb + (size_t)bh * 16000;
  __bf16* vp = vb + (size_t)bh * 16000;
  for (int i = tid; i < 575; i += 256) {
    if (i < 200)      *(bf16x8*)&qp[i * 80 + 72] = z;
    else if (i < 400) *(bf16x8*)&kp[(i - 200) * 80 + 72] = z;
    else              *(bf16x8*)&vp[14600 + (i - 400) * 8] = z;
  }
}

// ---------------- QKV projection GEMM: C = X[M,584]f32 * B[N,KP]^T --------
// r4 loop skeleton (256x128, 8 waves, one barrier/step) with A reg-staged
// DIRECTLY from f32 x (fuses cvt_x away): float4 loads -> bf16 cvt ->
// swizzled ds_write. B stays on global_load_lds. Loads for step t+2 issue
// at end of step t -> full-iteration slack before the post-MFMA vmcnt(0).
// LDS image identical to r4: As[row][u8] = global[row][u8 ^ (row&3)];
// read col cxr=(lq^(lr&3))*8 recovers global unit lq. k-tail (kt=18):
// only global cols 576..583 exist -> predicated loads, zero-fill rest.
__global__ __launch_bounds__(512, 4) void gemm_qkv(const float* __restrict__ X,
                                                   const __bf16* __restrict__ Bm,
                                                   __bf16* __restrict__ Q,
                                                   __bf16* __restrict__ Ko,
                                                   __bf16* __restrict__ V) {
  __shared__ __bf16 As[2][8192];   // [256][32] per buffer
  __shared__ __bf16 Bs[3][4096];   // [128][32]
  int tid = threadIdx.x;
  int id = blockIdx.x;
  int idp = (id & 7) * 350 + (id >> 3);    // 2800 = 8*350 bijective
  int bm = idp / 14, bn = idp - bm * 14;   // bn fast within a chunk
  int wid = tid >> 6, lane = tid & 63;
  int wm = (wid & 3) * 64, wn = (wid >> 2) * 64;
  int lr = lane & 15, lq = lane >> 4;
  // A reg-staging: lane owns row wid*32+(lane>>1), LDS units c80,c80+1
  int arow = wid * 32 + (lane >> 1);
  int r3 = arow & 3;
  int c80 = (lane & 1) * 2;
  int s0 = ((c80) ^ r3) * 8;               // swizzled global col offsets
  int s1 = ((c80 + 1) ^ r3) * 8;
  const float* xrow = X + (size_t)(bm * 256 + arow) * EMBED;
  // B staging: linear dest, pre-swizzled source (G21)
  int sw = ((lane & 3) ^ ((lane >> 2) & 3)) * 8;
  const __bf16* bB = Bm + (size_t)(bn * 128 + wid * 16 + (lane >> 2)) * KP + sw;
  f32x4 acc[4][4] = {};
  float4 ar0, ar1, ar2, ar3;

#define LOAD_A(kt)                                                      \
  do {                                                                  \
    if ((kt) < 18) {                                                    \
      const float* p_ = xrow + (kt) * 32;                               \
      ar0 = *(const float4*)(p_ + s0);                                  \
      ar1 = *(const float4*)(p_ + s0 + 4);                              \
      ar2 = *(const float4*)(p_ + s1);                                  \
      ar3 = *(const float4*)(p_ + s1 + 4);                              \
    } else {                                                            \
      float4 z_ = {0.f, 0.f, 0.f, 0.f};                                 \
      ar0 = (s0 == 0) ? *(const float4*)(xrow + 576) : z_;              \
      ar1 = (s0 == 0) ? *(const float4*)(xrow + 580) : z_;              \
      ar2 = (s1 == 0) ? *(const float4*)(xrow + 576) : z_;              \
      ar3 = (s1 == 0) ? *(const float4*)(xrow + 580) : z_;              \
    }                                                                   \
  } while (0)
#define CVT_WRITE(buf)                                                  \
  do {                                                                  \
    bf16x8 w0, w1;                                                      \
    w0[0]=(__bf16)ar0.x; w0[1]=(__bf16)ar0.y; w0[2]=(__bf16)ar0.z; w0[3]=(__bf16)ar0.w; \
    w0[4]=(__bf16)ar1.x; w0[5]=(__bf16)ar1.y; w0[6]=(__bf16)ar1.z; w0[7]=(__bf16)ar1.w; \
    w1[0]=(__bf16)ar2.x; w1[1]=(__bf16)ar2.y; w1[2]=(__bf16)ar2.z; w1[3]=(__bf16)ar2.w; \
    w1[4]=(__bf16)ar3.x; w1[5]=(__bf16)ar3.y; w1[6]=(__bf16)ar3.z; w1[7]=(__bf16)ar3.w; \
    *(bf16x8*)&As[buf][arow * 32 + c80 * 8] = w0;                       \
    *(bf16x8*)&As[buf][arow * 32 + c80 * 8 + 8] = w1;                   \
  } while (0)
#define STAGE_B(buf, kt) gld_lds16(Bs[buf] + wid * 512, bB + (kt) * 32)

  LOAD_A(0);
  STAGE_B(0, 0);
  asm volatile("s_waitcnt vmcnt(0)" ::: "memory");
  CVT_WRITE(0);
  LOAD_A(1);
  STAGE_B(1, 1);
  int cxr = (lq ^ (lr & 3)) * 8;
#pragma unroll
  for (int kt = 0; kt < 19; ++kt) {
    asm volatile("s_waitcnt lgkmcnt(0)" ::: "memory");
    __builtin_amdgcn_s_barrier();
    const __bf16* Ac = As[kt & 1];
    const __bf16* Bc = Bs[kt % 3];
    bf16x8 af[4], bfr[4];
#pragma unroll
    for (int i = 0; i < 4; ++i)
      af[i] = *(const bf16x8*)&Ac[(wm + i * 16 + lr) * 32 + cxr];
#pragma unroll
    for (int j = 0; j < 4; ++j)
      bfr[j] = *(const bf16x8*)&Bc[(wn + j * 16 + lr) * 32 + cxr];
    __builtin_amdgcn_s_setprio(1);
#pragma unroll
    for (int i = 0; i < 4; ++i)
#pragma unroll
      for (int j = 0; j < 4; ++j)
        acc[i][j] = __builtin_amdgcn_mfma_f32_16x16x32_bf16(af[i], bfr[j], acc[i][j], 0, 0, 0);
    __builtin_amdgcn_s_setprio(0);
    if (kt < 18) {
      // A(kt+1) regs + B(kt+1) LDS: issued a full iteration ago -> ~free
      asm volatile("s_waitcnt vmcnt(0)" ::: "memory");
      CVT_WRITE((kt + 1) & 1);   // buf read at kt-1; protected by barrier kt
      if (kt + 2 < 19) { LOAD_A(kt + 2); STAGE_B((kt + 2) % 3, kt + 2); }
    }
  }
#undef LOAD_A
#undef CVT_WRITE
#undef STAGE_B
  // ---- epilogue: slim index math ----
  int whichj[4], ojv[4];
  __bf16* Pj[4];
  bool okj[4];
#pragma unroll
  for (int j = 0; j < 4; ++j) {
    int n = bn * 128 + wn + j * 16 + lr;
    okj[j] = (n < NQKV);
    int nn = okj[j] ? n : 0;
    int which = nn / EMBED;
    int rem = nn - which * EMBED;
    int hh = rem / HS;
    int f = rem - hh * HS;
    whichj[j] = which;
    ojv[j] = (which == 2) ? (hh * 16000 + f * 200) : (hh * 16000 + f);
    Pj[j] = (which == 0) ? Q : (which == 1) ? Ko : V;
  }
#pragma unroll
  for (int i = 0; i < 4; ++i) {
    int m0 = bm * 256 + wm + i * 16 + lq * 4;  // multiple of 4
    int bb = m0 / CTX;
    int tt = m0 - bb * CTX;                    // multiple of 4 -> tt+3 <= 199
    int a_qk = bb * 128000 + tt * 80;
    int a_v  = bb * 128000 + tt;
#pragma unroll
    for (int j = 0; j < 4; ++j) {
      if (!okj[j]) continue;
      if (whichj[j] == 2) {
        bf16x4 v4;
#pragma unroll
        for (int r = 0; r < 4; ++r) v4[r] = (__bf16)acc[i][j][r];
        *(bf16x4*)&Pj[j][a_v + ojv[j]] = v4;   // 8B-aligned (tt%4==0)
      } else {
        int base = a_qk + ojv[j];
#pragma unroll
        for (int r = 0; r < 4; ++r)
          Pj[j][base + r * 80] = (__bf16)acc[i][j][r];
      }
    }
  }
}

// ---------------- MFMA flash attention: one block per (b,h) ---------------
// (r2 one-pass version restored: barrier-free, single-pass softmax,
//  causality-skipping; proven faster than the two-pass variant.)
__global__ __launch_bounds__(256, 4) void attn_kernel(const __bf16* __restrict__ q,
                                                      const __bf16* __restrict__ k,
                                                      const __bf16* __restrict__ v,
                                                      __bf16* __restrict__ o) {
  __shared__ __align__(16) __bf16 Ps[4][16 * PSS];
  int tid = threadIdx.x;
  int bh = blockIdx.x;
  int b = bh >> 3, h = bh & 7;
  const __bf16* qg = q + (size_t)bh * 16000;
  const __bf16* kg = k + (size_t)bh * 16000;
  const __bf16* vg = v + (size_t)bh * 16000;

  // zero output pad columns (once per (b,t); h==0 blocks only)
  if (h == 0) {
    bf16x8 z = {};
    for (int i = tid; i < CTX * 3; i += 256) {
      int t = i / 3, seg = i - t * 3;
      *(bf16x8*)&o[((size_t)(b * CTX + t)) * KP + EMBED + seg * 8] = z;
    }
  }

  int wid = tid >> 6, lane = tid & 63;
  int lr = lane & 15, g = lane >> 4;
  __bf16* Pw = Ps[wid];
  const float scale = 0.04138029443264672f;  // 584^-0.5

  // balanced strip map: units(s)=s+1 -> totals {22,23,24,22}
  int sl[4];
  sl[0] = 12 - wid;                   // 12,11,10,9
  sl[1] = (wid < 3) ? 6 + wid : 5;    // 6,7,8,5
  sl[2] = (wid < 3) ? 1 + wid : 4;    // 1,2,3,4
  sl[3] = (wid < 3) ? -1 : 0;         // -,-,-,0

#pragma unroll
  for (int si = 0; si < 4; ++si) {
    int s = sl[si];
    if (s < 0) continue;              // wave-uniform
    int row0 = s * 16;
    bf16x8 qf[3];
    qf[0] = *(const bf16x8*)&qg[(size_t)(row0 + lr) * HSQ + g * 8];
    qf[1] = *(const bf16x8*)&qg[(size_t)(row0 + lr) * HSQ + 32 + g * 8];
    qf[2] = (g < 2) ? *(const bf16x8*)&qg[(size_t)(row0 + lr) * HSQ + 64 + g * 8]
                    : bf16x8{};
    float sc[13][4];
#pragma unroll
    for (int nt = 0; nt < 13; ++nt) {
      if (nt > s) continue;           // wave-uniform skip
      f32x4 acc = {};
#pragma unroll
      for (int kc = 0; kc < 3; ++kc) {
        bf16x8 kf = *(const bf16x8*)&kg[(size_t)(nt * 16 + lr) * HSQ + kc * 32 + g * 8];
        acc = __builtin_amdgcn_mfma_f32_16x16x32_bf16(qf[kc], kf, acc, 0, 0, 0);
      }
#pragma unroll
      for (int r = 0; r < 4; ++r) {
        float val = acc[r] * scale;
        if (nt == s && lr > g * 4 + r) val = -1e30f;   // diagonal tile mask
        if (nt * 16 + lr >= CTX) val = -1e30f;         // keys beyond CTX
        sc[nt][r] = val;
      }
    }
    float mr[4], rs[4];
#pragma unroll
    for (int r = 0; r < 4; ++r) {
      float m = -1e30f;
#pragma unroll
      for (int nt = 0; nt < 13; ++nt)
        if (nt <= s) m = fmaxf(m, sc[nt][r]);
      mr[r] = m;
    }
#pragma unroll
    for (int off = 8; off; off >>= 1)
#pragma unroll
      for (int r = 0; r < 4; ++r)
        mr[r] = fmaxf(mr[r], __shfl_xor(mr[r], off, 64));
#pragma unroll
    for (int r = 0; r < 4; ++r) {
      float ssum = 0.f;
#pragma unroll
      for (int nt = 0; nt < 13; ++nt) {
        if (nt > s) continue;
        sc[nt][r] = __expf(sc[nt][r] - mr[r]);
        ssum += sc[nt][r];
      }
      rs[r] = ssum;
    }
#pragma unroll
    for (int off = 8; off; off >>= 1)
#pragma unroll
      for (int r = 0; r < 4; ++r) rs[r] += __shfl_xor(rs[r], off, 64);
#pragma unroll
    for (int nt = 0; nt < 13; ++nt) {
      if (nt > s) continue;
#pragma unroll
      for (int r = 0; r < 4; ++r)
        Pw[(g * 4 + r) * PSS + nt * 16 + lr] = (__bf16)sc[nt][r];
    }
    if ((s & 1) == 0) {
#pragma unroll
      for (int r = 0; r < 4; ++r)
        Pw[(g * 4 + r) * PSS + (s + 1) * 16 + lr] = (__bf16)0.f;
    }
    f32x4 ov[5];
#pragma unroll
    for (int nt = 0; nt < 5; ++nt) ov[nt] = f32x4{0.f, 0.f, 0.f, 0.f};
#pragma unroll
    for (int kc = 0; kc < 7; ++kc) {
      if (kc > s / 2) continue;       // only key tiles with nonzero P
      bf16x8 pf = *(const bf16x8*)&Pw[lr * PSS + kc * 32 + g * 8];
#pragma unroll
      for (int nt = 0; nt < 5; ++nt) {
        bf16x8 vf = *(const bf16x8*)&vg[(size_t)(nt * 16 + lr) * CTX + kc * 32 + g * 8];
        ov[nt] = __builtin_amdgcn_mfma_f32_16x16x32_bf16(pf, vf, ov[nt], 0, 0, 0);
      }
    }
    float inv[4];
#pragma unroll
    for (int r = 0; r < 4; ++r) inv[r] = 1.0f / rs[r];
#pragma unroll
    for (int nt = 0; nt < 5; ++nt) {
      int f = nt * 16 + lr;
      if (f < HS) {
#pragma unroll
        for (int r = 0; r < 4; ++r) {
          int t = row0 + g * 4 + r;
          if (t < CTX)
            o[((size_t)(b * CTX + t)) * KP + h * HS + f] =
                (__bf16)(ov[nt][r] * inv[r]);
        }
      }
    }
  }
}

// ---------------- output projection GEMM + bias, fp32 out -----------------
// (r4 winner, unchanged) 256x128 8-wave 3-buffer; 1000 = 8*125.
__global__ __launch_bounds__(512, 4) void gemm_out(const __bf16* __restrict__ A,
                                                   const __bf16* __restrict__ Bm,
                                                   const float* __restrict__ bias,
                                                   float* __restrict__ C) {
  constexpr int N = EMBED;
  __shared__ __bf16 As[3][8192];
  __shared__ __bf16 Bs[3][4096];
  int tid = threadIdx.x;
  int id = blockIdx.x;
  int idp = (id & 7) * 125 + (id >> 3);
  int bm = idp / 5, bn = idp - bm * 5;
  int wid = tid >> 6, lane = tid & 63;
  int wm = (wid & 3) * 64, wn = (wid >> 2) * 64;
  int lr = lane & 15, lq = lane >> 4;
  int sw = (((lane & 3) ^ ((lane >> 2) & 3))) * 8;
  const __bf16* aB = A  + (size_t)(bm * 256 + wid * 32 + (lane >> 2)) * KP + sw;
  const __bf16* bB = Bm + (size_t)(bn * 128 + wid * 16 + (lane >> 2)) * KP + sw;
  f32x4 acc[4][4] = {};

#define STAGE_OUT(buf, kt)                                        \
  do {                                                            \
    int k0_ = (kt) * 32;                                          \
    gld_lds16(As[buf] + wid * 1024,       aB + k0_);              \
    gld_lds16(As[buf] + wid * 1024 + 512, aB + 16 * KP + k0_);    \
    gld_lds16(Bs[buf] + wid * 512,        bB + k0_);              \
  } while (0)

  STAGE_OUT(0, 0);
  STAGE_OUT(1, 1);
  int cxr = (lq ^ (lr & 3)) * 8;
#pragma unroll
  for (int kt = 0; kt < 19; ++kt) {
    if (kt < 18) asm volatile("s_waitcnt vmcnt(3)" ::: "memory");
    else         asm volatile("s_waitcnt vmcnt(0)" ::: "memory");
    __builtin_amdgcn_s_barrier();
    if (kt + 2 < 19) STAGE_OUT((kt + 2) % 3, kt + 2);
    const __bf16* Ac = As[kt % 3];
    const __bf16* Bc = Bs[kt % 3];
    bf16x8 af[4], bfr[4];
#pragma unroll
    for (int i = 0; i < 4; ++i)
      af[i] = *(const bf16x8*)&Ac[(wm + i * 16 + lr) * 32 + cxr];
#pragma unroll
    for (int j = 0; j < 4; ++j)
      bfr[j] = *(const bf16x8*)&Bc[(wn + j * 16 + lr) * 32 + cxr];
    __builtin_amdgcn_s_setprio(1);
#pragma unroll
    for (int i = 0; i < 4; ++i)
#pragma unroll
      for (int j = 0; j < 4; ++j)
        acc[i][j] = __builtin_amdgcn_mfma_f32_16x16x32_bf16(af[i], bfr[j], acc[i][j], 0, 0, 0);
    __builtin_amdgcn_s_setprio(0);
  }
#undef STAGE_OUT
#pragma unroll
  for (int i = 0; i < 4; ++i) {
    int m = bm * 256 + wm + i * 16 + lq * 4;
#pragma unroll
    for (int j = 0; j < 4; ++j) {
      int n = bn * 128 + wn + j * 16 + lr;
      if (n < N) {
        float bval = bias[n];
#pragma unroll
        for (int r = 0; r < 4; ++r)
          C[(size_t)(m + r) * N + n] = acc[i][j][r] + bval;
      }
    }
  }
}

extern "C" void kernel_launch(void* const* d_in, const int* in_sizes, int n_in,
                              void* d_out, int out_size, void* d_ws, size_t ws_size,
                              hipStream_t stream) {
  const float* x  = (const float*)d_in[0];
  const float* Wq = (const float*)d_in[1];
  const float* Wk = (const float*)d_in[2];
  const float* Wv = (const float*)d_in[3];
  const float* Wo = (const float*)d_in[4];
  const float* bo = (const float*)d_in[5];
  float* out = (float*)d_out;

  // ws layout (bf16 elems), total 130,853,888 elems = 261.7 MB.
  __bf16* wcat = (__bf16*)d_ws;            // [2336*608]  = 1,420,288
  __bf16* vb   = wcat + 1420288ULL;        // [bh][f][200], 32,768,000
  __bf16* qb   = vb + 32768000ULL;         // [bh][t][80],  32,768,000
  __bf16* kb   = qb + 32768000ULL;         // [bh][t][80],  32,768,000
  __bf16* ab   = kb + 32768000ULL;         // [51200][608], 31,129,600 (attn out)

  pack_w_zero<<<2048, 256, 0, stream>>>(Wq, Wk, Wv, Wo, wcat, qb, kb, vb);
  gemm_qkv<<<2800, 512, 0, stream>>>(x, wcat, qb, kb, vb);
  attn_kernel<<<2048, 256, 0, stream>>>(qb, kb, vb, ab);
  gemm_out<<<1000, 512, 0, stream>>>(ab, wcat + 1752ULL * KP, bo, out);
}